// Round 1
// baseline (426.398 us; speedup 1.0000x reference)
//
#include <hip/hip_runtime.h>
#include <hip/hip_bf16.h>
#include <math.h>

#define D_MODEL 768
#define N_HEAD  12
#define SEQ     2048
#define BATCH   4
#define HD      64
#define BH      (BATCH*N_HEAD)

typedef __bf16 bf16;
typedef __bf16 bf16x4 __attribute__((ext_vector_type(4)));
typedef __bf16 bf16x8 __attribute__((ext_vector_type(8)));
typedef float  f32x4  __attribute__((ext_vector_type(4)));

__device__ __forceinline__ f32x4 mfma16(bf16x8 a, bf16x8 b, f32x4 c) {
    return __builtin_amdgcn_mfma_f32_16x16x32_bf16(a, b, c, 0, 0, 0);
}

// ---------------- prep kernels ----------------
__global__ void cvt_bf16(const float* __restrict__ in, bf16* __restrict__ out, int n) {
    int i = (blockIdx.x * blockDim.x + threadIdx.x) * 4;
    if (i < n) {
        float4 v = *(const float4*)(in + i);
        bf16x4 o;
        o[0] = (bf16)v.x; o[1] = (bf16)v.y; o[2] = (bf16)v.z; o[3] = (bf16)v.w;
        *(bf16x4*)(out + i) = o;
    }
}

// in [R][C] fp32 -> out [C][R] bf16
__global__ void transpose_cvt(const float* __restrict__ in, bf16* __restrict__ out, int R, int C) {
    int id = blockIdx.x * blockDim.x + threadIdx.x;
    if (id < R * C) {
        int r = id / C, c = id % C;
        out[c * R + r] = (bf16)in[id];
    }
}

// ---------------- GEMM: C = A[M,K] * Bt[N,K]^T + bias ----------------
// MODE 0: QKV epilogue (scatter to q/k row-major, v transposed), MODE 1: fp32 out
template<int MODE>
__global__ __launch_bounds__(256)
void gemm_bt(const bf16* __restrict__ A, const bf16* __restrict__ Bt,
             const float* __restrict__ bias,
             bf16* __restrict__ qo, bf16* __restrict__ ko, bf16* __restrict__ vto,
             float* __restrict__ outf,
             int M, int N, int K) {
    __shared__ bf16 As[128][40];
    __shared__ bf16 Bs[128][40];
    int tid = threadIdx.x;
    int wave = tid >> 6, lane = tid & 63;
    int wr = wave >> 1, wc = wave & 1;
    int lq = lane >> 4, lc = lane & 15;
    int mbase = blockIdx.x * 128, nbase = blockIdx.y * 128;
    f32x4 acc[4][4] = {};
    for (int kt = 0; kt < K; kt += 32) {
        #pragma unroll
        for (int i = 0; i < 2; ++i) {
            int c = tid + i * 256;
            int row = c >> 2, col = (c & 3) * 8;
            *(bf16x8*)&As[row][col] = *(const bf16x8*)&A[(long)(mbase + row) * K + kt + col];
            *(bf16x8*)&Bs[row][col] = *(const bf16x8*)&Bt[(long)(nbase + row) * K + kt + col];
        }
        __syncthreads();
        bf16x8 af[4], bfr[4];
        #pragma unroll
        for (int mf = 0; mf < 4; ++mf) af[mf]  = *(const bf16x8*)&As[wr * 64 + mf * 16 + lc][lq * 8];
        #pragma unroll
        for (int nf = 0; nf < 4; ++nf) bfr[nf] = *(const bf16x8*)&Bs[wc * 64 + nf * 16 + lc][lq * 8];
        #pragma unroll
        for (int mf = 0; mf < 4; ++mf)
            #pragma unroll
            for (int nf = 0; nf < 4; ++nf)
                acc[mf][nf] = mfma16(af[mf], bfr[nf], acc[mf][nf]);
        __syncthreads();
    }
    #pragma unroll
    for (int mf = 0; mf < 4; ++mf) {
        #pragma unroll
        for (int nf = 0; nf < 4; ++nf) {
            int n = nbase + wc * 64 + nf * 16 + lc;
            float bv = bias[n];
            #pragma unroll
            for (int r = 0; r < 4; ++r) {
                int m = mbase + wr * 64 + mf * 16 + lq * 4 + r;
                float v = acc[mf][nf][r] + bv;
                if (MODE == 0) {
                    int sect = n / 768, cc = n % 768;
                    int h = cc >> 6, d = cc & 63;
                    int b = m >> 11, t = m & 2047;
                    long bh = (long)b * N_HEAD + h;
                    if (sect == 0)      qo[(bh * SEQ + t) * HD + d] = (bf16)v;
                    else if (sect == 1) ko[(bh * SEQ + t) * HD + d] = (bf16)v;
                    else                vto[(bh * HD + d) * SEQ + t] = (bf16)v;
                } else {
                    outf[(long)m * N + n] = v;
                }
            }
        }
    }
}

// ---------------- flash attention ----------------
// grid: (qb 0..31, bh 0..47); 4 waves, each owns 16 q rows of the 64-row block
__global__ __launch_bounds__(256)
void attn_kernel(const bf16* __restrict__ qg, const bf16* __restrict__ kg,
                 const bf16* __restrict__ vtg, bf16* __restrict__ yg) {
    __shared__ bf16 Ks[32][72];
    __shared__ bf16 Vs[64][40];
    __shared__ bf16 Ps[4][16][40];
    int tid = threadIdx.x;
    int wave = tid >> 6, lane = tid & 63;
    int lq = lane >> 4, lc = lane & 15;
    int qb = blockIdx.x;
    int bh = blockIdx.y;
    int b = bh / N_HEAD, h = bh % N_HEAD;
    long koff = (long)bh * SEQ * HD;
    long voff = (long)bh * HD * SEQ;
    int qrow0 = qb * 64 + wave * 16;

    bf16x8 qf[2];
    qf[0] = *(const bf16x8*)&qg[koff + (long)(qrow0 + lc) * HD + lq * 8];
    qf[1] = *(const bf16x8*)&qg[koff + (long)(qrow0 + lc) * HD + 32 + lq * 8];

    f32x4 yacc[4] = {};
    float mrow[4], lrow[4];
    #pragma unroll
    for (int r = 0; r < 4; ++r) { mrow[r] = -INFINITY; lrow[r] = 0.f; }

    int nkt = (qb + 1) * 2;
    for (int kt = 0; kt < nkt; ++kt) {
        int k0 = kt * 32;
        __syncthreads();
        {
            int row = tid >> 3, col = (tid & 7) * 8;               // K tile 32x64
            *(bf16x8*)&Ks[row][col] = *(const bf16x8*)&kg[koff + (long)(k0 + row) * HD + col];
            int vrow = tid >> 2, vcol = (tid & 3) * 8;             // V^T tile 64x32
            *(bf16x8*)&Vs[vrow][vcol] = *(const bf16x8*)&vtg[voff + (long)vrow * SEQ + k0 + vcol];
        }
        __syncthreads();

        f32x4 s0 = {}, s1 = {};
        bf16x8 kf;
        kf = *(const bf16x8*)&Ks[lc][lq * 8];           s0 = mfma16(qf[0], kf, s0);
        kf = *(const bf16x8*)&Ks[lc][32 + lq * 8];      s0 = mfma16(qf[1], kf, s0);
        kf = *(const bf16x8*)&Ks[16 + lc][lq * 8];      s1 = mfma16(qf[0], kf, s1);
        kf = *(const bf16x8*)&Ks[16 + lc][32 + lq * 8]; s1 = mfma16(qf[1], kf, s1);

        #pragma unroll
        for (int r = 0; r < 4; ++r) {
            int qr = qrow0 + lq * 4 + r;
            float a0 = s0[r] * 0.125f, a1 = s1[r] * 0.125f;
            if (k0 + lc > qr)      a0 = -INFINITY;
            if (k0 + 16 + lc > qr) a1 = -INFINITY;
            float mx = fmaxf(a0, a1);
            mx = fmaxf(mx, __shfl_xor(mx, 1));
            mx = fmaxf(mx, __shfl_xor(mx, 2));
            mx = fmaxf(mx, __shfl_xor(mx, 4));
            mx = fmaxf(mx, __shfl_xor(mx, 8));
            float mnew = fmaxf(mrow[r], mx);
            float sc = __expf(mrow[r] - mnew);
            float p0 = __expf(a0 - mnew), p1 = __expf(a1 - mnew);
            float ps = p0 + p1;
            ps += __shfl_xor(ps, 1); ps += __shfl_xor(ps, 2);
            ps += __shfl_xor(ps, 4); ps += __shfl_xor(ps, 8);
            lrow[r] = lrow[r] * sc + ps;
            mrow[r] = mnew;
            #pragma unroll
            for (int dt = 0; dt < 4; ++dt) yacc[dt][r] *= sc;
            int prow = lq * 4 + r;
            Ps[wave][prow][lc]      = (bf16)p0;
            Ps[wave][prow][16 + lc] = (bf16)p1;
        }

        bf16x8 pf = *(const bf16x8*)&Ps[wave][lc][lq * 8];
        #pragma unroll
        for (int dt = 0; dt < 4; ++dt) {
            bf16x8 vf = *(const bf16x8*)&Vs[dt * 16 + lc][lq * 8];
            yacc[dt] = mfma16(pf, vf, yacc[dt]);
        }
    }

    #pragma unroll
    for (int r = 0; r < 4; ++r) {
        float inv = 1.f / lrow[r];
        int q = qrow0 + lq * 4 + r;
        long rowoff = ((long)b * SEQ + q) * D_MODEL + (long)h * HD;
        #pragma unroll
        for (int dt = 0; dt < 4; ++dt)
            yg[rowoff + dt * 16 + lc] = (bf16)(yacc[dt][r] * inv);
    }
}

extern "C" void kernel_launch(void* const* d_in, const int* in_sizes, int n_in,
                              void* d_out, int out_size, void* d_ws, size_t ws_size,
                              hipStream_t stream) {
    const float* x      = (const float*)d_in[0];
    const float* W_attn = (const float*)d_in[1];
    const float* b_attn = (const float*)d_in[2];
    const float* W_proj = (const float*)d_in[3];
    const float* b_proj = (const float*)d_in[4];
    float* out = (float*)d_out;

    char* ws = (char*)d_ws;
    size_t off = 0;
    auto alloc = [&](size_t bytes) { void* p = ws + off; off += (bytes + 255) & ~255ULL; return p; };
    bf16* xb  = (bf16*)alloc(8192ULL * 768 * 2);
    bf16* Wab = (bf16*)alloc(2304ULL * 768 * 2);
    bf16* Wpb = (bf16*)alloc(768ULL * 768 * 2);
    bf16* qb_ = (bf16*)alloc((size_t)BH * SEQ * HD * 2);
    bf16* kb_ = (bf16*)alloc((size_t)BH * SEQ * HD * 2);
    bf16* vtb = (bf16*)alloc((size_t)BH * SEQ * HD * 2);
    bf16* yb  = (bf16*)alloc(8192ULL * 768 * 2);

    hipLaunchKernelGGL(cvt_bf16, dim3((8192 * 768 / 4 + 255) / 256), dim3(256), 0, stream,
                       x, xb, 8192 * 768);
    hipLaunchKernelGGL(transpose_cvt, dim3((768 * 2304 + 255) / 256), dim3(256), 0, stream,
                       W_attn, Wab, 768, 2304);
    hipLaunchKernelGGL(transpose_cvt, dim3((768 * 768 + 255) / 256), dim3(256), 0, stream,
                       W_proj, Wpb, 768, 768);
    hipLaunchKernelGGL((gemm_bt<0>), dim3(64, 18), dim3(256), 0, stream,
                       xb, Wab, b_attn, qb_, kb_, vtb, (float*)nullptr, 8192, 2304, 768);
    hipLaunchKernelGGL(attn_kernel, dim3(32, 48), dim3(256), 0, stream,
                       qb_, kb_, vtb, yb);
    hipLaunchKernelGGL((gemm_bt<1>), dim3(64, 6), dim3(256), 0, stream,
                       yb, Wpb, b_proj, (bf16*)nullptr, (bf16*)nullptr, (bf16*)nullptr, out, 8192, 768, 768);
}

// Round 2
// 292.583 us; speedup vs baseline: 1.4574x; 1.4574x over previous
//
#include <hip/hip_runtime.h>
#include <hip/hip_bf16.h>
#include <math.h>

#define D_MODEL 768
#define N_HEAD  12
#define SEQ     2048
#define BATCH   4
#define HD      64
#define BH      (BATCH*N_HEAD)

typedef __bf16 bf16;
typedef __bf16 bf16x4 __attribute__((ext_vector_type(4)));
typedef __bf16 bf16x8 __attribute__((ext_vector_type(8)));
typedef float  f32x4  __attribute__((ext_vector_type(4)));

__device__ __forceinline__ f32x4 mfma16(bf16x8 a, bf16x8 b, f32x4 c) {
    return __builtin_amdgcn_mfma_f32_16x16x32_bf16(a, b, c, 0, 0, 0);
}

// ---------------- prep kernels ----------------
__global__ void cvt_bf16(const float* __restrict__ in, bf16* __restrict__ out, int n) {
    int i = (blockIdx.x * blockDim.x + threadIdx.x) * 4;
    if (i < n) {
        float4 v = *(const float4*)(in + i);
        bf16x4 o;
        o[0] = (bf16)v.x; o[1] = (bf16)v.y; o[2] = (bf16)v.z; o[3] = (bf16)v.w;
        *(bf16x4*)(out + i) = o;
    }
}

// in [R][C] fp32 -> out [C][R] bf16
__global__ void transpose_cvt(const float* __restrict__ in, bf16* __restrict__ out, int R, int C) {
    int id = blockIdx.x * blockDim.x + threadIdx.x;
    if (id < R * C) {
        int r = id / C, c = id % C;
        out[c * R + r] = (bf16)in[id];
    }
}

// ---------------- GEMM: C = A[M,K] * Bt[N,K]^T + bias ----------------
// MODE 0: QKV epilogue (scatter to q/k row-major, v transposed), MODE 1: fp32 out
template<int MODE>
__global__ __launch_bounds__(256)
void gemm_bt(const bf16* __restrict__ A, const bf16* __restrict__ Bt,
             const float* __restrict__ bias,
             bf16* __restrict__ qo, bf16* __restrict__ ko, bf16* __restrict__ vto,
             float* __restrict__ outf,
             int M, int N, int K) {
    __shared__ bf16 As[128][40];
    __shared__ bf16 Bs[128][40];
    int tid = threadIdx.x;
    int wave = tid >> 6, lane = tid & 63;
    int wr = wave >> 1, wc = wave & 1;
    int lq = lane >> 4, lc = lane & 15;
    int mbase = blockIdx.x * 128, nbase = blockIdx.y * 128;
    f32x4 acc[4][4] = {};
    for (int kt = 0; kt < K; kt += 32) {
        #pragma unroll
        for (int i = 0; i < 2; ++i) {
            int c = tid + i * 256;
            int row = c >> 2, col = (c & 3) * 8;
            *(bf16x8*)&As[row][col] = *(const bf16x8*)&A[(long)(mbase + row) * K + kt + col];
            *(bf16x8*)&Bs[row][col] = *(const bf16x8*)&Bt[(long)(nbase + row) * K + kt + col];
        }
        __syncthreads();
        bf16x8 af[4], bfr[4];
        #pragma unroll
        for (int mf = 0; mf < 4; ++mf) af[mf]  = *(const bf16x8*)&As[wr * 64 + mf * 16 + lc][lq * 8];
        #pragma unroll
        for (int nf = 0; nf < 4; ++nf) bfr[nf] = *(const bf16x8*)&Bs[wc * 64 + nf * 16 + lc][lq * 8];
        #pragma unroll
        for (int mf = 0; mf < 4; ++mf)
            #pragma unroll
            for (int nf = 0; nf < 4; ++nf)
                acc[mf][nf] = mfma16(af[mf], bfr[nf], acc[mf][nf]);
        __syncthreads();
    }
    #pragma unroll
    for (int mf = 0; mf < 4; ++mf) {
        #pragma unroll
        for (int nf = 0; nf < 4; ++nf) {
            int n = nbase + wc * 64 + nf * 16 + lc;
            float bv = bias[n];
            #pragma unroll
            for (int r = 0; r < 4; ++r) {
                int m = mbase + wr * 64 + mf * 16 + lq * 4 + r;
                float v = acc[mf][nf][r] + bv;
                if (MODE == 0) {
                    int sect = n / 768, cc = n % 768;
                    int h = cc >> 6, d = cc & 63;
                    int b = m >> 11, t = m & 2047;
                    long bh = (long)b * N_HEAD + h;
                    if (sect == 0)      qo[(bh * SEQ + t) * HD + d] = (bf16)v;
                    else if (sect == 1) ko[(bh * SEQ + t) * HD + d] = (bf16)v;
                    else                vto[(bh * HD + d) * SEQ + t] = (bf16)v;
                } else {
                    outf[(long)m * N + n] = v;
                }
            }
        }
    }
}

// ---------------- flash attention (swapped QK^T, KVBLK=64) ----------------
// grid: (qb reversed 0..31, bh 0..47); 4 waves, each owns 16 q rows (q = lane&15)
__global__ __launch_bounds__(256)
void attn_kernel(const bf16* __restrict__ qg, const bf16* __restrict__ kg,
                 const bf16* __restrict__ vtg, bf16* __restrict__ yg) {
    __shared__ bf16 Ks[64][72];   // [key][d]
    __shared__ bf16 Vs[64][72];   // [d][key]  (V^T)
    __shared__ bf16 Ps[4][16][72];// per-wave [q][key]
    int tid = threadIdx.x;
    int wave = tid >> 6, lane = tid & 63;
    int lq = lane >> 4, lc = lane & 15;
    int qb = gridDim.x - 1 - blockIdx.x;   // heavy blocks first
    int bh = blockIdx.y;
    int b = bh / N_HEAD, h = bh % N_HEAD;
    long koff = (long)bh * SEQ * HD;
    long voff = (long)bh * HD * SEQ;
    int qrow0 = qb * 64 + wave * 16;
    int qglob = qrow0 + lc;

    // Q fragment: lane holds Q[q=lc][d = lq*8 .. +7] (+32 for second half)
    bf16x8 qf[2];
    qf[0] = *(const bf16x8*)&qg[koff + (long)qglob * HD + lq * 8];
    qf[1] = *(const bf16x8*)&qg[koff + (long)qglob * HD + 32 + lq * 8];

    f32x4 yacc[4] = {};
    float m2 = -INFINITY, lsum = 0.f;
    const float SC = 0.18033688f;  // 0.125 * log2(e) -> softmax in base-2 domain

    int nkt = qb + 1;
    for (int kt = 0; kt < nkt; ++kt) {
        int k0 = kt * 64;
        __syncthreads();
        {   // stage K [64][64] and V^T [64][64]; each thread: one row-quarter (16 elems) each
            int row = tid >> 2, c0 = (tid & 3) * 16;
            *(bf16x8*)&Ks[row][c0]     = *(const bf16x8*)&kg[koff + (long)(k0 + row) * HD + c0];
            *(bf16x8*)&Ks[row][c0 + 8] = *(const bf16x8*)&kg[koff + (long)(k0 + row) * HD + c0 + 8];
            *(bf16x8*)&Vs[row][c0]     = *(const bf16x8*)&vtg[voff + (long)row * SEQ + k0 + c0];
            *(bf16x8*)&Vs[row][c0 + 8] = *(const bf16x8*)&vtg[voff + (long)row * SEQ + k0 + c0 + 8];
        }
        __syncthreads();

        // S^T = K · Q^T : lane holds S[q=lc][k = k0 + sub*16 + lq*4 + r]
        f32x4 st[4];
        __builtin_amdgcn_s_setprio(1);
        #pragma unroll
        for (int sub = 0; sub < 4; ++sub) {
            bf16x8 kf0 = *(const bf16x8*)&Ks[sub * 16 + lc][lq * 8];
            bf16x8 kf1 = *(const bf16x8*)&Ks[sub * 16 + lc][32 + lq * 8];
            f32x4 s = {};
            s = mfma16(kf0, qf[0], s);
            s = mfma16(kf1, qf[1], s);
            st[sub] = s;
        }
        __builtin_amdgcn_s_setprio(0);

        // scale to base-2, causal mask, lane-local 16-wide softmax piece
        float pmax = -INFINITY;
        #pragma unroll
        for (int sub = 0; sub < 4; ++sub)
            #pragma unroll
            for (int r = 0; r < 4; ++r) {
                int k = k0 + sub * 16 + lq * 4 + r;
                float v = (k <= qglob) ? st[sub][r] * SC : -INFINITY;
                st[sub][r] = v;
                pmax = fmaxf(pmax, v);
            }
        pmax = fmaxf(pmax, __shfl_xor(pmax, 16));
        pmax = fmaxf(pmax, __shfl_xor(pmax, 32));
        float mnew = fmaxf(m2, pmax);
        float sc = __builtin_amdgcn_exp2f(m2 - mnew);
        #pragma unroll
        for (int dt = 0; dt < 4; ++dt) yacc[dt] *= sc;
        float psum = 0.f;
        #pragma unroll
        for (int sub = 0; sub < 4; ++sub) {
            bf16x4 pk;
            #pragma unroll
            for (int r = 0; r < 4; ++r) {
                float p = __builtin_amdgcn_exp2f(st[sub][r] - mnew);
                psum += p;
                pk[r] = (bf16)p;
            }
            *(bf16x4*)&Ps[wave][lc][sub * 16 + lq * 4] = pk;
        }
        psum += __shfl_xor(psum, 16);
        psum += __shfl_xor(psum, 32);
        lsum = lsum * sc + psum;
        m2 = mnew;

        // Y^T += V^T · P^T : lane holds Y[q=lc][d = dt*16 + lq*4 + r]
        bf16x8 pf0 = *(const bf16x8*)&Ps[wave][lc][lq * 8];
        bf16x8 pf1 = *(const bf16x8*)&Ps[wave][lc][32 + lq * 8];
        __builtin_amdgcn_s_setprio(1);
        #pragma unroll
        for (int dt = 0; dt < 4; ++dt) {
            bf16x8 v0 = *(const bf16x8*)&Vs[dt * 16 + lc][lq * 8];
            bf16x8 v1 = *(const bf16x8*)&Vs[dt * 16 + lc][32 + lq * 8];
            yacc[dt] = mfma16(v0, pf0, yacc[dt]);
            yacc[dt] = mfma16(v1, pf1, yacc[dt]);
        }
        __builtin_amdgcn_s_setprio(0);
    }

    float inv = 1.f / lsum;
    long rowoff = ((long)b * SEQ + qglob) * D_MODEL + (long)h * HD;
    #pragma unroll
    for (int dt = 0; dt < 4; ++dt) {
        bf16x4 o;
        #pragma unroll
        for (int r = 0; r < 4; ++r) o[r] = (bf16)(yacc[dt][r] * inv);
        *(bf16x4*)&yg[rowoff + dt * 16 + lq * 4] = o;
    }
}

extern "C" void kernel_launch(void* const* d_in, const int* in_sizes, int n_in,
                              void* d_out, int out_size, void* d_ws, size_t ws_size,
                              hipStream_t stream) {
    const float* x      = (const float*)d_in[0];
    const float* W_attn = (const float*)d_in[1];
    const float* b_attn = (const float*)d_in[2];
    const float* W_proj = (const float*)d_in[3];
    const float* b_proj = (const float*)d_in[4];
    float* out = (float*)d_out;

    char* ws = (char*)d_ws;
    size_t off = 0;
    auto alloc = [&](size_t bytes) { void* p = ws + off; off += (bytes + 255) & ~255ULL; return p; };
    bf16* xb  = (bf16*)alloc(8192ULL * 768 * 2);
    bf16* Wab = (bf16*)alloc(2304ULL * 768 * 2);
    bf16* Wpb = (bf16*)alloc(768ULL * 768 * 2);
    bf16* qb_ = (bf16*)alloc((size_t)BH * SEQ * HD * 2);
    bf16* kb_ = (bf16*)alloc((size_t)BH * SEQ * HD * 2);
    bf16* vtb = (bf16*)alloc((size_t)BH * SEQ * HD * 2);
    bf16* yb  = (bf16*)alloc(8192ULL * 768 * 2);

    hipLaunchKernelGGL(cvt_bf16, dim3((8192 * 768 / 4 + 255) / 256), dim3(256), 0, stream,
                       x, xb, 8192 * 768);
    hipLaunchKernelGGL(transpose_cvt, dim3((768 * 2304 + 255) / 256), dim3(256), 0, stream,
                       W_attn, Wab, 768, 2304);
    hipLaunchKernelGGL(transpose_cvt, dim3((768 * 768 + 255) / 256), dim3(256), 0, stream,
                       W_proj, Wpb, 768, 768);
    hipLaunchKernelGGL((gemm_bt<0>), dim3(64, 18), dim3(256), 0, stream,
                       xb, Wab, b_attn, qb_, kb_, vtb, (float*)nullptr, 8192, 2304, 768);
    hipLaunchKernelGGL(attn_kernel, dim3(32, 48), dim3(256), 0, stream,
                       qb_, kb_, vtb, yb);
    hipLaunchKernelGGL((gemm_bt<1>), dim3(64, 6), dim3(256), 0, stream,
                       yb, Wpb, b_proj, (bf16*)nullptr, (bf16*)nullptr, (bf16*)nullptr, out, 8192, 768, 768);
}

// Round 3
// 279.340 us; speedup vs baseline: 1.5265x; 1.0474x over previous
//
#include <hip/hip_runtime.h>
#include <hip/hip_bf16.h>
#include <math.h>

#define D_MODEL 768
#define N_HEAD  12
#define SEQ     2048
#define BATCH   4
#define HD      64
#define BH      (BATCH*N_HEAD)

typedef __bf16 bf16;
typedef __bf16 bf16x4 __attribute__((ext_vector_type(4)));
typedef __bf16 bf16x8 __attribute__((ext_vector_type(8)));
typedef float  f32x4  __attribute__((ext_vector_type(4)));
typedef unsigned int u32;

__device__ __forceinline__ f32x4 mfma16(bf16x8 a, bf16x8 b, f32x4 c) {
    return __builtin_amdgcn_mfma_f32_16x16x32_bf16(a, b, c, 0, 0, 0);
}

// async global->LDS, 16B per lane; LDS dest = wave-uniform base + lane*16
__device__ __forceinline__ void gload16(const void* g, void* l) {
    __builtin_amdgcn_global_load_lds((const __attribute__((address_space(1))) u32*)g,
                                     (__attribute__((address_space(3))) u32*)l, 16, 0, 0);
}

// ---------------- prep kernels ----------------
__global__ void cvt_bf16(const float* __restrict__ in, bf16* __restrict__ out, int n) {
    int i = (blockIdx.x * blockDim.x + threadIdx.x) * 4;
    if (i < n) {
        float4 v = *(const float4*)(in + i);
        bf16x4 o;
        o[0] = (bf16)v.x; o[1] = (bf16)v.y; o[2] = (bf16)v.z; o[3] = (bf16)v.w;
        *(bf16x4*)(out + i) = o;
    }
}

// in [R][C] fp32 -> out [C][R] bf16, LDS-tiled 64x64 (R,C multiples of 64)
__global__ __launch_bounds__(256)
void transpose_cvt(const float* __restrict__ in, bf16* __restrict__ out, int R, int C) {
    __shared__ float tile[64][65];
    int tid = threadIdx.x;
    int tr = blockIdx.y * 64, tc = blockIdx.x * 64;
    int r0 = tid >> 4, c0 = (tid & 15) * 4;
    #pragma unroll
    for (int i = 0; i < 4; ++i) {
        float4 v = *(const float4*)&in[(long)(tr + r0 + i * 16) * C + tc + c0];
        tile[r0 + i * 16][c0 + 0] = v.x;
        tile[r0 + i * 16][c0 + 1] = v.y;
        tile[r0 + i * 16][c0 + 2] = v.z;
        tile[r0 + i * 16][c0 + 3] = v.w;
    }
    __syncthreads();
    int orr = (tid & 15) * 4;
    #pragma unroll
    for (int i = 0; i < 4; ++i) {
        int oc = (tid >> 4) + i * 16;
        bf16x4 o;
        #pragma unroll
        for (int j = 0; j < 4; ++j) o[j] = (bf16)tile[orr + j][oc];
        *(bf16x4*)&out[(long)(tc + oc) * R + tr + orr] = o;
    }
}

// ---------------- GEMM (m97 structure): C = A[M,K] * Bt[N,K]^T + bias ----------------
// MODE 0: QKV epilogue (scatter to q/k row-major, v transposed), MODE 1: fp32 out
template<int MODE>
__global__ __launch_bounds__(256)
void gemm_bt(const bf16* __restrict__ A, const bf16* __restrict__ Bt,
             const float* __restrict__ bias,
             bf16* __restrict__ qo, bf16* __restrict__ ko, bf16* __restrict__ vto,
             float* __restrict__ outf,
             int M, int N, int K) {
    __shared__ bf16 As[128 * 32];   // linear, row stride 32 el (64B)
    __shared__ bf16 Bs[128 * 32];
    int tid = threadIdx.x;
    int wave = tid >> 6, lane = tid & 63;
    int wr = wave >> 1, wc = wave & 1;
    int lq = lane >> 4, lc = lane & 15;
    int mbase = blockIdx.x * 128, nbase = blockIdx.y * 128;
    // staging map: instr j of wave w covers rows w*32 + j*16 + (lane>>2), col (lane&3)*8
    int srow = wave * 32 + (lane >> 2), scol = (lane & 3) * 8;
    const bf16* aS = A  + (long)(mbase + srow) * K + scol;
    const bf16* bS = Bt + (long)(nbase + srow) * K + scol;
    char* AsB = (char*)As + wave * 2048;
    char* BsB = (char*)Bs + wave * 2048;
    f32x4 acc[4][4] = {};
    for (int kt = 0; kt < K; kt += 32) {
        gload16(aS + kt,               AsB);
        gload16(aS + 16 * (long)K + kt, AsB + 1024);
        gload16(bS + kt,               BsB);
        gload16(bS + 16 * (long)K + kt, BsB + 1024);
        __syncthreads();
        bf16x8 af[4], bfr[4];
        #pragma unroll
        for (int mf = 0; mf < 4; ++mf)
            af[mf]  = *(const bf16x8*)((char*)As + (wr * 64 + mf * 16 + lc) * 64 + lq * 16);
        #pragma unroll
        for (int nf = 0; nf < 4; ++nf)
            bfr[nf] = *(const bf16x8*)((char*)Bs + (wc * 64 + nf * 16 + lc) * 64 + lq * 16);
        __builtin_amdgcn_s_setprio(1);
        #pragma unroll
        for (int mf = 0; mf < 4; ++mf)
            #pragma unroll
            for (int nf = 0; nf < 4; ++nf)
                acc[mf][nf] = mfma16(af[mf], bfr[nf], acc[mf][nf]);
        __builtin_amdgcn_s_setprio(0);
        __syncthreads();
    }
    #pragma unroll
    for (int mf = 0; mf < 4; ++mf) {
        #pragma unroll
        for (int nf = 0; nf < 4; ++nf) {
            int n = nbase + wc * 64 + nf * 16 + lc;
            float bv = bias[n];
            #pragma unroll
            for (int r = 0; r < 4; ++r) {
                int m = mbase + wr * 64 + mf * 16 + lq * 4 + r;
                float v = acc[mf][nf][r] + bv;
                if (MODE == 0) {
                    int sect = n / 768, cc = n % 768;
                    int h = cc >> 6, d = cc & 63;
                    int b = m >> 11, t = m & 2047;
                    long bh = (long)b * N_HEAD + h;
                    if (sect == 0)      qo[(bh * SEQ + t) * HD + d] = (bf16)v;
                    else if (sect == 1) ko[(bh * SEQ + t) * HD + d] = (bf16)v;
                    else                vto[(bh * HD + d) * SEQ + t] = (bf16)v;
                } else {
                    outf[(long)m * N + n] = v;
                }
            }
        }
    }
}

// ---------------- flash attention (swapped QK^T, KVBLK=64, gload_lds dbuf) ----------------
// grid: (qb reversed 0..31, bh 0..47); 4 waves, each owns 16 q rows (q = lane&15)
__global__ __launch_bounds__(256)
void attn_kernel(const bf16* __restrict__ qg, const bf16* __restrict__ kg,
                 const bf16* __restrict__ vtg, bf16* __restrict__ yg) {
    __shared__ bf16 Ks[2][64 * 64];   // [key][d], XOR-swizzled cols
    __shared__ bf16 Vs[2][64 * 64];   // [d][key], XOR-swizzled cols
    __shared__ bf16 Ps[4][16][72];    // per-wave [q][key], padded
    int tid = threadIdx.x;
    int wave = tid >> 6, lane = tid & 63;
    int lq = lane >> 4, lc = lane & 15;
    int qb = gridDim.x - 1 - blockIdx.x;   // heavy blocks first
    int bh = blockIdx.y;
    int b = bh / N_HEAD, h = bh % N_HEAD;
    long koff = (long)bh * SEQ * HD;
    long voff = (long)bh * HD * SEQ;
    int qrow0 = qb * 64 + wave * 16;
    int qglob = qrow0 + lc;

    // stage addressing: instr j of wave w covers LDS rows w*16 + j*8 + (lane>>3)
    // source col pre-swizzled: ((lane&7) ^ (lane>>3)) * 8  (row&7 == lane>>3)
    int srow0 = wave * 16 + (lane >> 3);
    int scolsw = ((lane & 7) ^ (lane >> 3)) << 3;

    auto stageKV = [&](int kt, int buf) {
        int k0 = kt * 64;
        char* KsB = (char*)&Ks[buf][0] + wave * 2048;
        char* VsB = (char*)&Vs[buf][0] + wave * 2048;
        gload16(kg + koff + (long)(k0 + srow0) * HD + scolsw,      KsB);
        gload16(kg + koff + (long)(k0 + srow0 + 8) * HD + scolsw,  KsB + 1024);
        gload16(vtg + voff + (long)srow0 * SEQ + k0 + scolsw,      VsB);
        gload16(vtg + voff + (long)(srow0 + 8) * SEQ + k0 + scolsw, VsB + 1024);
    };

    // Q fragment: lane holds Q[q=lc][d = lq*8 .. +7] (+32 for second half)
    bf16x8 qf[2];
    qf[0] = *(const bf16x8*)&qg[koff + (long)qglob * HD + lq * 8];
    qf[1] = *(const bf16x8*)&qg[koff + (long)qglob * HD + 32 + lq * 8];

    f32x4 yacc[4] = {};
    float m2 = -INFINITY, lsum = 0.f;
    const float SC = 0.18033688f;  // 0.125 * log2(e) -> softmax in base-2 domain
    int swz = (lane & 7) << 3;     // read-side XOR (row&7 == lc&7 == lane&7)

    int nkt = qb + 1;
    stageKV(0, 0);
    for (int kt = 0; kt < nkt; ++kt) {
        int cur = kt & 1;
        if (kt + 1 < nkt) {
            stageKV(kt + 1, cur ^ 1);
            asm volatile("s_waitcnt vmcnt(4)" ::: "memory");
        } else {
            asm volatile("s_waitcnt vmcnt(0)" ::: "memory");
        }
        __builtin_amdgcn_s_barrier();
        __builtin_amdgcn_sched_barrier(0);
        const char* KsC = (const char*)&Ks[cur][0];
        const char* VsC = (const char*)&Vs[cur][0];
        int k0 = kt * 64;

        // S^T = K · Q^T : lane holds S[q=lc][k = k0 + sub*16 + lq*4 + r]
        f32x4 st[4];
        __builtin_amdgcn_s_setprio(1);
        #pragma unroll
        for (int sub = 0; sub < 4; ++sub) {
            bf16x8 kf0 = *(const bf16x8*)(KsC + ((sub * 16 + lc) * 64 + ((lq * 8) ^ swz)) * 2);
            bf16x8 kf1 = *(const bf16x8*)(KsC + ((sub * 16 + lc) * 64 + ((32 + lq * 8) ^ swz)) * 2);
            f32x4 s = {};
            s = mfma16(kf0, qf[0], s);
            s = mfma16(kf1, qf[1], s);
            st[sub] = s;
        }
        __builtin_amdgcn_s_setprio(0);

        // scale to base-2, causal mask, lane-local softmax piece
        float pmax = -INFINITY;
        #pragma unroll
        for (int sub = 0; sub < 4; ++sub)
            #pragma unroll
            for (int r = 0; r < 4; ++r) {
                int k = k0 + sub * 16 + lq * 4 + r;
                float v = (k <= qglob) ? st[sub][r] * SC : -INFINITY;
                st[sub][r] = v;
                pmax = fmaxf(pmax, v);
            }
        pmax = fmaxf(pmax, __shfl_xor(pmax, 16));
        pmax = fmaxf(pmax, __shfl_xor(pmax, 32));
        float mnew = fmaxf(m2, pmax);
        float sc = __builtin_amdgcn_exp2f(m2 - mnew);
        #pragma unroll
        for (int dt = 0; dt < 4; ++dt) yacc[dt] *= sc;
        float psum = 0.f;
        #pragma unroll
        for (int sub = 0; sub < 4; ++sub) {
            bf16x4 pk;
            #pragma unroll
            for (int r = 0; r < 4; ++r) {
                float p = __builtin_amdgcn_exp2f(st[sub][r] - mnew);
                psum += p;
                pk[r] = (bf16)p;
            }
            *(bf16x4*)&Ps[wave][lc][sub * 16 + lq * 4] = pk;
        }
        psum += __shfl_xor(psum, 16);
        psum += __shfl_xor(psum, 32);
        lsum = lsum * sc + psum;
        m2 = mnew;

        // Y^T += V^T · P^T : lane holds Y[q=lc][d = dt*16 + lq*4 + r]
        bf16x8 pf0 = *(const bf16x8*)&Ps[wave][lc][lq * 8];
        bf16x8 pf1 = *(const bf16x8*)&Ps[wave][lc][32 + lq * 8];
        __builtin_amdgcn_s_setprio(1);
        #pragma unroll
        for (int dt = 0; dt < 4; ++dt) {
            bf16x8 v0 = *(const bf16x8*)(VsC + ((dt * 16 + lc) * 64 + ((lq * 8) ^ swz)) * 2);
            bf16x8 v1 = *(const bf16x8*)(VsC + ((dt * 16 + lc) * 64 + ((32 + lq * 8) ^ swz)) * 2);
            yacc[dt] = mfma16(v0, pf0, yacc[dt]);
            yacc[dt] = mfma16(v1, pf1, yacc[dt]);
        }
        __builtin_amdgcn_s_setprio(0);
        __builtin_amdgcn_sched_barrier(0);
        __builtin_amdgcn_s_barrier();
    }

    float inv = 1.f / lsum;
    long rowoff = ((long)b * SEQ + qglob) * D_MODEL + (long)h * HD;
    #pragma unroll
    for (int dt = 0; dt < 4; ++dt) {
        bf16x4 o;
        #pragma unroll
        for (int r = 0; r < 4; ++r) o[r] = (bf16)(yacc[dt][r] * inv);
        *(bf16x4*)&yg[rowoff + dt * 16 + lq * 4] = o;
    }
}

extern "C" void kernel_launch(void* const* d_in, const int* in_sizes, int n_in,
                              void* d_out, int out_size, void* d_ws, size_t ws_size,
                              hipStream_t stream) {
    const float* x      = (const float*)d_in[0];
    const float* W_attn = (const float*)d_in[1];
    const float* b_attn = (const float*)d_in[2];
    const float* W_proj = (const float*)d_in[3];
    const float* b_proj = (const float*)d_in[4];
    float* out = (float*)d_out;

    char* ws = (char*)d_ws;
    size_t off = 0;
    auto alloc = [&](size_t bytes) { void* p = ws + off; off += (bytes + 255) & ~255ULL; return p; };
    bf16* xb  = (bf16*)alloc(8192ULL * 768 * 2);
    bf16* Wab = (bf16*)alloc(2304ULL * 768 * 2);
    bf16* Wpb = (bf16*)alloc(768ULL * 768 * 2);
    bf16* qb_ = (bf16*)alloc((size_t)BH * SEQ * HD * 2);
    bf16* kb_ = (bf16*)alloc((size_t)BH * SEQ * HD * 2);
    bf16* vtb = (bf16*)alloc((size_t)BH * SEQ * HD * 2);
    bf16* yb  = (bf16*)alloc(8192ULL * 768 * 2);

    hipLaunchKernelGGL(cvt_bf16, dim3((8192 * 768 / 4 + 255) / 256), dim3(256), 0, stream,
                       x, xb, 8192 * 768);
    hipLaunchKernelGGL(transpose_cvt, dim3(2304 / 64, 768 / 64), dim3(256), 0, stream,
                       W_attn, Wab, 768, 2304);
    hipLaunchKernelGGL(transpose_cvt, dim3(768 / 64, 768 / 64), dim3(256), 0, stream,
                       W_proj, Wpb, 768, 768);
    hipLaunchKernelGGL((gemm_bt<0>), dim3(64, 18), dim3(256), 0, stream,
                       xb, Wab, b_attn, qb_, kb_, vtb, (float*)nullptr, 8192, 2304, 768);
    hipLaunchKernelGGL(attn_kernel, dim3(32, 48), dim3(256), 0, stream,
                       qb_, kb_, vtb, yb);
    hipLaunchKernelGGL((gemm_bt<1>), dim3(64, 6), dim3(256), 0, stream,
                       yb, Wpb, b_proj, (bf16*)nullptr, (bf16*)nullptr, (bf16*)nullptr, out, 8192, 768, 768);
}

// Round 5
// 237.940 us; speedup vs baseline: 1.7920x; 1.1740x over previous
//
#include <hip/hip_runtime.h>
#include <hip/hip_bf16.h>
#include <math.h>

#define D_MODEL 768
#define N_HEAD  12
#define SEQ     2048
#define BATCH   4
#define HD      64
#define BH      (BATCH*N_HEAD)

typedef __bf16 bf16;
typedef __bf16 bf16x4 __attribute__((ext_vector_type(4)));
typedef __bf16 bf16x8 __attribute__((ext_vector_type(8)));
typedef float  f32x4  __attribute__((ext_vector_type(4)));
typedef unsigned int u32;

__device__ __forceinline__ f32x4 mfma16(bf16x8 a, bf16x8 b, f32x4 c) {
    return __builtin_amdgcn_mfma_f32_16x16x32_bf16(a, b, c, 0, 0, 0);
}

// async global->LDS, 16B per lane; LDS dest = wave-uniform base + lane*16
__device__ __forceinline__ void gload16(const void* g, void* l) {
    __builtin_amdgcn_global_load_lds((const __attribute__((address_space(1))) u32*)g,
                                     (__attribute__((address_space(3))) u32*)l, 16, 0, 0);
}

// ---------------- prep kernels ----------------
__global__ void cvt_bf16(const float* __restrict__ in, bf16* __restrict__ out, int n) {
    int i = (blockIdx.x * blockDim.x + threadIdx.x) * 4;
    if (i < n) {
        float4 v = *(const float4*)(in + i);
        bf16x4 o;
        o[0] = (bf16)v.x; o[1] = (bf16)v.y; o[2] = (bf16)v.z; o[3] = (bf16)v.w;
        *(bf16x4*)(out + i) = o;
    }
}

// in [R][C] fp32 -> out [C][R] bf16, LDS-tiled 64x64 (R,C multiples of 64)
__global__ __launch_bounds__(256)
void transpose_cvt(const float* __restrict__ in, bf16* __restrict__ out, int R, int C) {
    __shared__ float tile[64][65];
    int tid = threadIdx.x;
    int tr = blockIdx.y * 64, tc = blockIdx.x * 64;
    int r0 = tid >> 4, c0 = (tid & 15) * 4;
    #pragma unroll
    for (int i = 0; i < 4; ++i) {
        float4 v = *(const float4*)&in[(long)(tr + r0 + i * 16) * C + tc + c0];
        tile[r0 + i * 16][c0 + 0] = v.x;
        tile[r0 + i * 16][c0 + 1] = v.y;
        tile[r0 + i * 16][c0 + 2] = v.z;
        tile[r0 + i * 16][c0 + 3] = v.w;
    }
    __syncthreads();
    int orr = (tid & 15) * 4;
    #pragma unroll
    for (int i = 0; i < 4; ++i) {
        int oc = (tid >> 4) + i * 16;
        bf16x4 o;
        #pragma unroll
        for (int j = 0; j < 4; ++j) o[j] = (bf16)tile[orr + j][oc];
        *(bf16x4*)&out[(long)(tc + oc) * R + tr + orr] = o;
    }
}

// ---------------- GEMM (m97 structure): C = A[M,K] * Bt[N,K]^T + bias ----------------
// MODE 0: QKV epilogue (q pre-scaled by 1/8; scatter q/k row-major, v transposed), MODE 1: fp32 out
template<int MODE>
__global__ __launch_bounds__(256)
void gemm_bt(const bf16* __restrict__ A, const bf16* __restrict__ Bt,
             const float* __restrict__ bias,
             bf16* __restrict__ qo, bf16* __restrict__ ko, bf16* __restrict__ vto,
             float* __restrict__ outf,
             int M, int N, int K) {
    __shared__ bf16 As[128 * 32];   // linear, row stride 32 el (64B)
    __shared__ bf16 Bs[128 * 32];
    int tid = threadIdx.x;
    int wave = tid >> 6, lane = tid & 63;
    int wr = wave >> 1, wc = wave & 1;
    int lq = lane >> 4, lc = lane & 15;
    int mbase = blockIdx.x * 128, nbase = blockIdx.y * 128;
    int srow = wave * 32 + (lane >> 2), scol = (lane & 3) * 8;
    const bf16* aS = A  + (long)(mbase + srow) * K + scol;
    const bf16* bS = Bt + (long)(nbase + srow) * K + scol;
    char* AsB = (char*)As + wave * 2048;
    char* BsB = (char*)Bs + wave * 2048;
    f32x4 acc[4][4] = {};
    for (int kt = 0; kt < K; kt += 32) {
        gload16(aS + kt,                AsB);
        gload16(aS + 16 * (long)K + kt, AsB + 1024);
        gload16(bS + kt,                BsB);
        gload16(bS + 16 * (long)K + kt, BsB + 1024);
        __syncthreads();
        bf16x8 af[4], bfr[4];
        #pragma unroll
        for (int mf = 0; mf < 4; ++mf)
            af[mf]  = *(const bf16x8*)((char*)As + (wr * 64 + mf * 16 + lc) * 64 + lq * 16);
        #pragma unroll
        for (int nf = 0; nf < 4; ++nf)
            bfr[nf] = *(const bf16x8*)((char*)Bs + (wc * 64 + nf * 16 + lc) * 64 + lq * 16);
        __builtin_amdgcn_s_setprio(1);
        #pragma unroll
        for (int mf = 0; mf < 4; ++mf)
            #pragma unroll
            for (int nf = 0; nf < 4; ++nf)
                acc[mf][nf] = mfma16(af[mf], bfr[nf], acc[mf][nf]);
        __builtin_amdgcn_s_setprio(0);
        __syncthreads();
    }
    #pragma unroll
    for (int mf = 0; mf < 4; ++mf) {
        #pragma unroll
        for (int nf = 0; nf < 4; ++nf) {
            int n = nbase + wc * 64 + nf * 16 + lc;
            float bv = bias[n];
            int m0 = mbase + wr * 64 + mf * 16 + lq * 4;
            if (MODE == 0) {
                int sect = n / 768, cc = n % 768;
                int h = cc >> 6, d = cc & 63;
                int b = m0 >> 11, t0 = m0 & 2047;
                long bh = (long)b * N_HEAD + h;
                if (sect == 0) {
                    #pragma unroll
                    for (int r = 0; r < 4; ++r)
                        qo[(bh * SEQ + t0 + r) * HD + d] = (bf16)((acc[mf][nf][r] + bv) * 0.125f);
                } else if (sect == 1) {
                    #pragma unroll
                    for (int r = 0; r < 4; ++r)
                        ko[(bh * SEQ + t0 + r) * HD + d] = (bf16)(acc[mf][nf][r] + bv);
                } else {
                    bf16x4 o;
                    #pragma unroll
                    for (int r = 0; r < 4; ++r) o[r] = (bf16)(acc[mf][nf][r] + bv);
                    *(bf16x4*)&vto[(bh * HD + d) * SEQ + t0] = o;
                }
            } else {
                #pragma unroll
                for (int r = 0; r < 4; ++r)
                    outf[(long)(m0 + r) * N + n] = acc[mf][nf][r] + bv;
            }
        }
    }
}

// ---------------- flash attention (swapped QK^T, QBLK=128, KVBLK=64) ----------------
// grid: (qb reversed 0..15, bh 0..47); 4 waves; each wave owns q-halves A/B of 16 rows
__global__ __launch_bounds__(256, 4)
void attn_kernel(const bf16* __restrict__ qg, const bf16* __restrict__ kg,
                 const bf16* __restrict__ vtg, bf16* __restrict__ yg) {
    __shared__ bf16 Ks[64 * 64];   // [key][d], XOR-swizzled cols
    __shared__ bf16 Vs[64 * 64];   // [d][key], XOR-swizzled cols
    __shared__ bf16 Ps[4][16][72]; // per-wave [q][key], padded
    int tid = threadIdx.x;
    int wave = tid >> 6, lane = tid & 63;
    int lq = lane >> 4, lc = lane & 15;
    int qb = gridDim.x - 1 - blockIdx.x;   // heavy blocks first
    int bh = blockIdx.y;
    int b = bh / N_HEAD, h = bh % N_HEAD;
    long koff = (long)bh * SEQ * HD;
    long voff = (long)bh * HD * SEQ;
    int q0 = qb * 128 + wave * 16 + lc;    // half A
    int q1 = q0 + 64;                      // half B

    // stage addressing: instr j of wave w covers LDS rows w*16 + j*8 + (lane>>3)
    int srow0 = wave * 16 + (lane >> 3);
    int scolsw = ((lane & 7) ^ (lane >> 3)) << 3;   // pre-swizzled source col

    // Q fragments (Q pre-scaled by 1/8): lane holds Q[q][d = lq*8..+7] (+32)
    bf16x8 qfA[2], qfB[2];
    qfA[0] = *(const bf16x8*)&qg[koff + (long)q0 * HD + lq * 8];
    qfA[1] = *(const bf16x8*)&qg[koff + (long)q0 * HD + 32 + lq * 8];
    qfB[0] = *(const bf16x8*)&qg[koff + (long)q1 * HD + lq * 8];
    qfB[1] = *(const bf16x8*)&qg[koff + (long)q1 * HD + 32 + lq * 8];

    f32x4 yA[4] = {}, yB[4] = {};
    float mA = -INFINITY, lsA = 0.f, mB = -INFINITY, lsB = 0.f;
    const float L2E = 1.4426950408889634f;
    int swz = (lane & 7) << 3;             // read-side XOR
    const char* KsC = (const char*)Ks;
    const char* VsC = (const char*)Vs;
    int k0 = 0;

    auto half = [&](const bf16x8* qf, int qrow, bool diag,
                    float& m2, float& lsum, f32x4* yacc) {
        f32x4 st[4];
        __builtin_amdgcn_s_setprio(1);
        #pragma unroll
        for (int sub = 0; sub < 4; ++sub) {
            bf16x8 kf0 = *(const bf16x8*)(KsC + ((sub * 16 + lc) * 64 + ((lq * 8) ^ swz)) * 2);
            bf16x8 kf1 = *(const bf16x8*)(KsC + ((sub * 16 + lc) * 64 + ((32 + lq * 8) ^ swz)) * 2);
            f32x4 s = {};
            s = mfma16(kf0, qf[0], s);
            s = mfma16(kf1, qf[1], s);
            st[sub] = s;
        }
        __builtin_amdgcn_s_setprio(0);
        float pmax = -INFINITY;
        if (diag) {
            #pragma unroll
            for (int sub = 0; sub < 4; ++sub)
                #pragma unroll
                for (int r = 0; r < 4; ++r) {
                    int k = k0 + sub * 16 + lq * 4 + r;
                    if (k > qrow) st[sub][r] = -INFINITY;
                    pmax = fmaxf(pmax, st[sub][r]);
                }
        } else {
            #pragma unroll
            for (int sub = 0; sub < 4; ++sub)
                #pragma unroll
                for (int r = 0; r < 4; ++r) pmax = fmaxf(pmax, st[sub][r]);
        }
        pmax = fmaxf(pmax, __shfl_xor(pmax, 16));
        pmax = fmaxf(pmax, __shfl_xor(pmax, 32));
        if (!__all(pmax <= m2 + 5.5452f)) {     // defer-max, THR = 8 nat-log units
            float mnew = fmaxf(m2, pmax);
            float sc = __builtin_amdgcn_exp2f((m2 - mnew) * L2E);
            #pragma unroll
            for (int dt = 0; dt < 4; ++dt) yacc[dt] *= sc;
            lsum *= sc;
            m2 = mnew;
        }
        float m2L = m2 * L2E;
        float psum = 0.f;
        #pragma unroll
        for (int sub = 0; sub < 4; ++sub) {
            bf16x4 pk;
            #pragma unroll
            for (int r = 0; r < 4; ++r) {
                float p = __builtin_amdgcn_exp2f(__builtin_fmaf(st[sub][r], L2E, -m2L));
                psum += p;
                pk[r] = (bf16)p;
            }
            *(bf16x4*)&Ps[wave][lc][sub * 16 + lq * 4] = pk;
        }
        psum += __shfl_xor(psum, 16);
        psum += __shfl_xor(psum, 32);
        lsum += psum;
        bf16x8 pf0 = *(const bf16x8*)&Ps[wave][lc][lq * 8];
        bf16x8 pf1 = *(const bf16x8*)&Ps[wave][lc][32 + lq * 8];
        __builtin_amdgcn_s_setprio(1);
        #pragma unroll
        for (int dt = 0; dt < 4; ++dt) {
            bf16x8 v0 = *(const bf16x8*)(VsC + ((dt * 16 + lc) * 64 + ((lq * 8) ^ swz)) * 2);
            bf16x8 v1 = *(const bf16x8*)(VsC + ((dt * 16 + lc) * 64 + ((32 + lq * 8) ^ swz)) * 2);
            yacc[dt] = mfma16(v0, pf0, yacc[dt]);
            yacc[dt] = mfma16(v1, pf1, yacc[dt]);
        }
        __builtin_amdgcn_s_setprio(0);
    };

    int nkt = 2 * qb + 2;
    for (int kt = 0; kt < nkt; ++kt) {
        k0 = kt * 64;
        {   // stage K [64][64] and V^T [64][64] via global_load_lds
            char* KsB = (char*)Ks + wave * 2048;
            char* VsB = (char*)Vs + wave * 2048;
            gload16(kg + koff + (long)(k0 + srow0) * HD + scolsw,       KsB);
            gload16(kg + koff + (long)(k0 + srow0 + 8) * HD + scolsw,   KsB + 1024);
            gload16(vtg + voff + (long)srow0 * SEQ + k0 + scolsw,       VsB);
            gload16(vtg + voff + (long)(srow0 + 8) * SEQ + k0 + scolsw, VsB + 1024);
        }
        __syncthreads();
        if (kt <= 2 * qb) half(qfA, q0, kt == 2 * qb, mA, lsA, yA);
        half(qfB, q1, kt == nkt - 1, mB, lsB, yB);
        __syncthreads();
    }

    float invA = 1.f / lsA, invB = 1.f / lsB;
    long rowA = ((long)b * SEQ + q0) * D_MODEL + (long)h * HD;
    long rowB = ((long)b * SEQ + q1) * D_MODEL + (long)h * HD;
    #pragma unroll
    for (int dt = 0; dt < 4; ++dt) {
        bf16x4 oA, oB;
        #pragma unroll
        for (int r = 0; r < 4; ++r) {
            oA[r] = (bf16)(yA[dt][r] * invA);
            oB[r] = (bf16)(yB[dt][r] * invB);
        }
        *(bf16x4*)&yg[rowA + dt * 16 + lq * 4] = oA;
        *(bf16x4*)&yg[rowB + dt * 16 + lq * 4] = oB;
    }
}

extern "C" void kernel_launch(void* const* d_in, const int* in_sizes, int n_in,
                              void* d_out, int out_size, void* d_ws, size_t ws_size,
                              hipStream_t stream) {
    const float* x      = (const float*)d_in[0];
    const float* W_attn = (const float*)d_in[1];
    const float* b_attn = (const float*)d_in[2];
    const float* W_proj = (const float*)d_in[3];
    const float* b_proj = (const float*)d_in[4];
    float* out = (float*)d_out;

    char* ws = (char*)d_ws;
    size_t off = 0;
    auto alloc = [&](size_t bytes) { void* p = ws + off; off += (bytes + 255) & ~255ULL; return p; };
    bf16* xb  = (bf16*)alloc(8192ULL * 768 * 2);
    bf16* Wab = (bf16*)alloc(2304ULL * 768 * 2);
    bf16* Wpb = (bf16*)alloc(768ULL * 768 * 2);
    bf16* qb_ = (bf16*)alloc((size_t)BH * SEQ * HD * 2);
    bf16* kb_ = (bf16*)alloc((size_t)BH * SEQ * HD * 2);
    bf16* vtb = (bf16*)alloc((size_t)BH * SEQ * HD * 2);
    bf16* yb  = (bf16*)alloc(8192ULL * 768 * 2);

    hipLaunchKernelGGL(cvt_bf16, dim3((8192 * 768 / 4 + 255) / 256), dim3(256), 0, stream,
                       x, xb, 8192 * 768);
    hipLaunchKernelGGL(transpose_cvt, dim3(2304 / 64, 768 / 64), dim3(256), 0, stream,
                       W_attn, Wab, 768, 2304);
    hipLaunchKernelGGL(transpose_cvt, dim3(768 / 64, 768 / 64), dim3(256), 0, stream,
                       W_proj, Wpb, 768, 768);
    hipLaunchKernelGGL((gemm_bt<0>), dim3(64, 18), dim3(256), 0, stream,
                       xb, Wab, b_attn, qb_, kb_, vtb, (float*)nullptr, 8192, 2304, 768);
    hipLaunchKernelGGL(attn_kernel, dim3(16, 48), dim3(256), 0, stream,
                       qb_, kb_, vtb, yb);
    hipLaunchKernelGGL((gemm_bt<1>), dim3(64, 6), dim3(256), 0, stream,
                       yb, Wpb, b_proj, (bf16*)nullptr, (bf16*)nullptr, (bf16*)nullptr, out, 8192, 768, 768);
}

// Round 6
// 211.143 us; speedup vs baseline: 2.0195x; 1.1269x over previous
//
#include <hip/hip_runtime.h>
#include <hip/hip_bf16.h>
#include <math.h>

#define D_MODEL 768
#define N_HEAD  12
#define SEQ     2048
#define BATCH   4
#define HD      64
#define BH      (BATCH*N_HEAD)

typedef __bf16 bf16;
typedef __bf16 bf16x4 __attribute__((ext_vector_type(4)));
typedef __bf16 bf16x8 __attribute__((ext_vector_type(8)));
typedef float  f32x4  __attribute__((ext_vector_type(4)));
typedef float  f32x16 __attribute__((ext_vector_type(16)));
typedef unsigned int u32;

__device__ __forceinline__ f32x4 mfma16(bf16x8 a, bf16x8 b, f32x4 c) {
    return __builtin_amdgcn_mfma_f32_16x16x32_bf16(a, b, c, 0, 0, 0);
}
__device__ __forceinline__ f32x16 mfma32(bf16x8 a, bf16x8 b, f32x16 c) {
    return __builtin_amdgcn_mfma_f32_32x32x16_bf16(a, b, c, 0, 0, 0);
}

// async global->LDS, 16B per lane; LDS dest = wave-uniform base + lane*16
__device__ __forceinline__ void gload16(const void* g, void* l) {
    __builtin_amdgcn_global_load_lds((const __attribute__((address_space(1))) u32*)g,
                                     (__attribute__((address_space(3))) u32*)l, 16, 0, 0);
}

// ---------------- prep kernels ----------------
__global__ void cvt_bf16(const float* __restrict__ in, bf16* __restrict__ out, int n) {
    int i = (blockIdx.x * blockDim.x + threadIdx.x) * 4;
    if (i < n) {
        float4 v = *(const float4*)(in + i);
        bf16x4 o;
        o[0] = (bf16)v.x; o[1] = (bf16)v.y; o[2] = (bf16)v.z; o[3] = (bf16)v.w;
        *(bf16x4*)(out + i) = o;
    }
}

// in [R][C] fp32 -> out [C][R] bf16, LDS-tiled 64x64 (R,C multiples of 64)
__global__ __launch_bounds__(256)
void transpose_cvt(const float* __restrict__ in, bf16* __restrict__ out, int R, int C) {
    __shared__ float tile[64][65];
    int tid = threadIdx.x;
    int tr = blockIdx.y * 64, tc = blockIdx.x * 64;
    int r0 = tid >> 4, c0 = (tid & 15) * 4;
    #pragma unroll
    for (int i = 0; i < 4; ++i) {
        float4 v = *(const float4*)&in[(long)(tr + r0 + i * 16) * C + tc + c0];
        tile[r0 + i * 16][c0 + 0] = v.x;
        tile[r0 + i * 16][c0 + 1] = v.y;
        tile[r0 + i * 16][c0 + 2] = v.z;
        tile[r0 + i * 16][c0 + 3] = v.w;
    }
    __syncthreads();
    int orr = (tid & 15) * 4;
    #pragma unroll
    for (int i = 0; i < 4; ++i) {
        int oc = (tid >> 4) + i * 16;
        bf16x4 o;
        #pragma unroll
        for (int j = 0; j < 4; ++j) o[j] = (bf16)tile[orr + j][oc];
        *(bf16x4*)&out[(long)(tc + oc) * R + tr + orr] = o;
    }
}

// ---------------- GEMM (m97 structure): C = A[M,K] * Bt[N,K]^T + bias ----------------
// MODE 0: QKV epilogue (q pre-scaled by 0.125*log2e; scatter q/k row-major, v transposed), MODE 1: fp32 out
template<int MODE>
__global__ __launch_bounds__(256)
void gemm_bt(const bf16* __restrict__ A, const bf16* __restrict__ Bt,
             const float* __restrict__ bias,
             bf16* __restrict__ qo, bf16* __restrict__ ko, bf16* __restrict__ vto,
             float* __restrict__ outf,
             int M, int N, int K) {
    __shared__ bf16 As[128 * 32];   // linear, row stride 32 el (64B)
    __shared__ bf16 Bs[128 * 32];
    int tid = threadIdx.x;
    int wave = tid >> 6, lane = tid & 63;
    int wr = wave >> 1, wc = wave & 1;
    int lq = lane >> 4, lc = lane & 15;
    int mbase = blockIdx.x * 128, nbase = blockIdx.y * 128;
    int srow = wave * 32 + (lane >> 2), scol = (lane & 3) * 8;
    const bf16* aS = A  + (long)(mbase + srow) * K + scol;
    const bf16* bS = Bt + (long)(nbase + srow) * K + scol;
    char* AsB = (char*)As + wave * 2048;
    char* BsB = (char*)Bs + wave * 2048;
    f32x4 acc[4][4] = {};
    for (int kt = 0; kt < K; kt += 32) {
        gload16(aS + kt,                AsB);
        gload16(aS + 16 * (long)K + kt, AsB + 1024);
        gload16(bS + kt,                BsB);
        gload16(bS + 16 * (long)K + kt, BsB + 1024);
        __syncthreads();
        bf16x8 af[4], bfr[4];
        #pragma unroll
        for (int mf = 0; mf < 4; ++mf)
            af[mf]  = *(const bf16x8*)((char*)As + (wr * 64 + mf * 16 + lc) * 64 + lq * 16);
        #pragma unroll
        for (int nf = 0; nf < 4; ++nf)
            bfr[nf] = *(const bf16x8*)((char*)Bs + (wc * 64 + nf * 16 + lc) * 64 + lq * 16);
        __builtin_amdgcn_s_setprio(1);
        #pragma unroll
        for (int mf = 0; mf < 4; ++mf)
            #pragma unroll
            for (int nf = 0; nf < 4; ++nf)
                acc[mf][nf] = mfma16(af[mf], bfr[nf], acc[mf][nf]);
        __builtin_amdgcn_s_setprio(0);
        __syncthreads();
    }
    #pragma unroll
    for (int mf = 0; mf < 4; ++mf) {
        #pragma unroll
        for (int nf = 0; nf < 4; ++nf) {
            int n = nbase + wc * 64 + nf * 16 + lc;
            float bv = bias[n];
            int m0 = mbase + wr * 64 + mf * 16 + lq * 4;
            if (MODE == 0) {
                int sect = n / 768, cc = n % 768;
                int h = cc >> 6, d = cc & 63;
                int b = m0 >> 11, t0 = m0 & 2047;
                long bh = (long)b * N_HEAD + h;
                if (sect == 0) {
                    #pragma unroll
                    for (int r = 0; r < 4; ++r)
                        qo[(bh * SEQ + t0 + r) * HD + d] = (bf16)((acc[mf][nf][r] + bv) * 0.18033688f);
                } else if (sect == 1) {
                    #pragma unroll
                    for (int r = 0; r < 4; ++r)
                        ko[(bh * SEQ + t0 + r) * HD + d] = (bf16)(acc[mf][nf][r] + bv);
                } else {
                    bf16x4 o;
                    #pragma unroll
                    for (int r = 0; r < 4; ++r) o[r] = (bf16)(acc[mf][nf][r] + bv);
                    *(bf16x4*)&vto[(bh * HD + d) * SEQ + t0] = o;
                }
            } else {
                #pragma unroll
                for (int r = 0; r < 4; ++r)
                    outf[(long)(m0 + r) * N + n] = acc[mf][nf][r] + bv;
            }
        }
    }
}

// ---------------- flash attention: 32x32 MFMA, in-register softmax, paired q-tiles ----------------
// grid: (bh 0..47, j 0..15). Waves 0-1: q-tile j (j+1 KV tiles); waves 2-3: q-tile 31-j (32-j tiles).
// Each wave owns 32 q rows (q = tile*64 + (wave&1)*32 + lane&31). KV staged once, shared.
__global__ __launch_bounds__(256, 3)
void attn_kernel(const bf16* __restrict__ qg, const bf16* __restrict__ kg,
                 const bf16* __restrict__ vtg, bf16* __restrict__ yg) {
    __shared__ bf16 Ks[64 * 64];   // [key][d], XOR-swizzled 16B groups
    __shared__ bf16 Vs[64 * 64];   // [d][key]
    int tid = threadIdx.x;
    int wave = tid >> 6, lane = tid & 63;
    int q5 = lane & 31, h = lane >> 5;
    int bh = blockIdx.x, j = blockIdx.y;
    int b = bh / N_HEAD, hh = bh % N_HEAD;
    int wp = wave >> 1;
    int myt     = wp ? 31 - j : j;
    int mytiles = wp ? 32 - j : j + 1;
    int nkt = 32 - j;
    long koff = (long)bh * SEQ * HD;
    long voff = (long)bh * HD * SEQ;
    int qrow = myt * 64 + (wave & 1) * 32 + q5;

    // Q B-frags (pre-scaled by 0.125*log2e): col q = lane&31, k(d) = s*16 + h*8 + 0..7
    bf16x8 qf[4];
    #pragma unroll
    for (int s = 0; s < 4; ++s)
        qf[s] = *(const bf16x8*)&qg[koff + (long)qrow * HD + s * 16 + h * 8];

    f32x16 y0 = {}, y1 = {};
    float m2 = -INFINITY, lsum = 0.f;

    int srow0 = wave * 16 + (lane >> 3);
    int scolsw = ((lane & 7) ^ (lane >> 3)) << 3;   // pre-swizzled source col (elems)
    int rsw = lane & 7;                              // read-side XOR on 16B-group index
    const char* KsC = (const char*)Ks;
    const char* VsC = (const char*)Vs;

    for (int kt = 0; kt < nkt; ++kt) {
        int k0 = kt * 64;
        {   // stage K [64][64] and V^T [64][64] (all 4 waves)
            char* KsB = (char*)Ks + wave * 2048;
            char* VsB = (char*)Vs + wave * 2048;
            gload16(kg + koff + (long)(k0 + srow0) * HD + scolsw,       KsB);
            gload16(kg + koff + (long)(k0 + srow0 + 8) * HD + scolsw,   KsB + 1024);
            gload16(vtg + voff + (long)srow0 * SEQ + k0 + scolsw,       VsB);
            gload16(vtg + voff + (long)(srow0 + 8) * SEQ + k0 + scolsw, VsB + 1024);
        }
        __syncthreads();
        if (kt < mytiles) {
            // S^T = K·Q^T: lane holds S[key-rows][q=q5]; s0 keys k0+0..31, s1 keys k0+32..63
            f32x16 s0 = {}, s1 = {};
            __builtin_amdgcn_s_setprio(1);
            #pragma unroll
            for (int s = 0; s < 4; ++s) {
                bf16x8 kf0 = *(const bf16x8*)(KsC + q5 * 128        + (((s * 2 + h) ^ rsw) << 4));
                bf16x8 kf1 = *(const bf16x8*)(KsC + (32 + q5) * 128 + (((s * 2 + h) ^ rsw) << 4));
                s0 = mfma32(kf0, qf[s], s0);
                s1 = mfma32(kf1, qf[s], s1);
            }
            __builtin_amdgcn_s_setprio(0);
            if (kt == mytiles - 1) {   // diagonal tile: causal mask
                #pragma unroll
                for (int r = 0; r < 16; ++r) {
                    int ka = k0 + (r & 3) + 8 * (r >> 2) + 4 * h;
                    if (ka > qrow)      s0[r] = -INFINITY;
                    if (ka + 32 > qrow) s1[r] = -INFINITY;
                }
            }
            float pmax = s0[0];
            #pragma unroll
            for (int r = 1; r < 16; ++r) pmax = fmaxf(pmax, s0[r]);
            #pragma unroll
            for (int r = 0; r < 16; ++r) pmax = fmaxf(pmax, s1[r]);
            pmax = fmaxf(pmax, __shfl_xor(pmax, 32));
            if (!__all(pmax <= m2 + 11.5f)) {   // defer-max (base-2 units)
                float mnew = fmaxf(m2, pmax);
                float sc = __builtin_amdgcn_exp2f(m2 - mnew);
                #pragma unroll
                for (int r = 0; r < 16; ++r) { y0[r] *= sc; y1[r] *= sc; }
                lsum *= sc;
                m2 = mnew;
            }
            float psum = 0.f;
            u32 d0a[4], d1a[4], d0b[4], d1b[4];
            #pragma unroll
            for (int m = 0; m < 4; ++m) {
                union { bf16x4 v; u32 w[2]; } pa, pb;
                #pragma unroll
                for (int rr = 0; rr < 4; ++rr) {
                    float p0 = __builtin_amdgcn_exp2f(s0[4 * m + rr] - m2);
                    float p1 = __builtin_amdgcn_exp2f(s1[4 * m + rr] - m2);
                    psum += p0 + p1;
                    pa.v[rr] = (bf16)p0; pb.v[rr] = (bf16)p1;
                }
                d0a[m] = pa.w[0]; d1a[m] = pa.w[1];
                d0b[m] = pb.w[0]; d1b[m] = pb.w[1];
            }
            psum += __shfl_xor(psum, 32);
            lsum += psum;
            u32 e0a[4], e1a[4], e0b[4], e1b[4];
            #pragma unroll
            for (int m = 0; m < 4; ++m) {
                e0a[m] = __shfl_xor(d0a[m], 32); e1a[m] = __shfl_xor(d1a[m], 32);
                e0b[m] = __shfl_xor(d0b[m], 32); e1b[m] = __shfl_xor(d1b[m], 32);
            }
            // Y^T += V^T·P^T: PV A-frag slot s needs keys s*16 + 8h + 0..7
            __builtin_amdgcn_s_setprio(1);
            #pragma unroll
            for (int s = 0; s < 4; ++s) {
                int m0 = 2 * (s & 1), m1 = m0 + 1;
                union { bf16x8 v; u32 w[4]; } fr;
                if (s < 2) {
                    fr.w[0] = h ? e0a[m1] : d0a[m0];
                    fr.w[1] = h ? e1a[m1] : d1a[m0];
                    fr.w[2] = h ? d0a[m1] : e0a[m0];
                    fr.w[3] = h ? d1a[m1] : e1a[m0];
                } else {
                    fr.w[0] = h ? e0b[m1] : d0b[m0];
                    fr.w[1] = h ? e1b[m1] : d1b[m0];
                    fr.w[2] = h ? d0b[m1] : e0b[m0];
                    fr.w[3] = h ? d1b[m1] : e1b[m0];
                }
                bf16x8 v0 = *(const bf16x8*)(VsC + q5 * 128        + (((s * 2 + h) ^ rsw) << 4));
                bf16x8 v1 = *(const bf16x8*)(VsC + (32 + q5) * 128 + (((s * 2 + h) ^ rsw) << 4));
                y0 = mfma32(v0, fr.v, y0);
                y1 = mfma32(v1, fr.v, y1);
            }
            __builtin_amdgcn_s_setprio(0);
        }
        __syncthreads();
    }

    // epilogue: lane writes q = qrow; d = dh*32 + 8m + 4h + rr
    float inv = 1.f / lsum;
    long rowoff = ((long)b * SEQ + qrow) * D_MODEL + (long)hh * HD;
    #pragma unroll
    for (int m = 0; m < 4; ++m) {
        bf16x4 o0, o1;
        #pragma unroll
        for (int rr = 0; rr < 4; ++rr) {
            o0[rr] = (bf16)(y0[4 * m + rr] * inv);
            o1[rr] = (bf16)(y1[4 * m + rr] * inv);
        }
        *(bf16x4*)&yg[rowoff + 8 * m + 4 * h]      = o0;
        *(bf16x4*)&yg[rowoff + 32 + 8 * m + 4 * h] = o1;
    }
}

extern "C" void kernel_launch(void* const* d_in, const int* in_sizes, int n_in,
                              void* d_out, int out_size, void* d_ws, size_t ws_size,
                              hipStream_t stream) {
    const float* x      = (const float*)d_in[0];
    const float* W_attn = (const float*)d_in[1];
    const float* b_attn = (const float*)d_in[2];
    const float* W_proj = (const float*)d_in[3];
    const float* b_proj = (const float*)d_in[4];
    float* out = (float*)d_out;

    char* ws = (char*)d_ws;
    size_t off = 0;
    auto alloc = [&](size_t bytes) { void* p = ws + off; off += (bytes + 255) & ~255ULL; return p; };
    bf16* xb  = (bf16*)alloc(8192ULL * 768 * 2);
    bf16* Wab = (bf16*)alloc(2304ULL * 768 * 2);
    bf16* Wpb = (bf16*)alloc(768ULL * 768 * 2);
    bf16* qb_ = (bf16*)alloc((size_t)BH * SEQ * HD * 2);
    bf16* kb_ = (bf16*)alloc((size_t)BH * SEQ * HD * 2);
    bf16* vtb = (bf16*)alloc((size_t)BH * SEQ * HD * 2);
    bf16* yb  = (bf16*)alloc(8192ULL * 768 * 2);

    hipLaunchKernelGGL(cvt_bf16, dim3((8192 * 768 / 4 + 255) / 256), dim3(256), 0, stream,
                       x, xb, 8192 * 768);
    hipLaunchKernelGGL(transpose_cvt, dim3(2304 / 64, 768 / 64), dim3(256), 0, stream,
                       W_attn, Wab, 768, 2304);
    hipLaunchKernelGGL(transpose_cvt, dim3(768 / 64, 768 / 64), dim3(256), 0, stream,
                       W_proj, Wpb, 768, 768);
    hipLaunchKernelGGL((gemm_bt<0>), dim3(64, 18), dim3(256), 0, stream,
                       xb, Wab, b_attn, qb_, kb_, vtb, (float*)nullptr, 8192, 2304, 768);
    hipLaunchKernelGGL(attn_kernel, dim3(48, 16), dim3(256), 0, stream,
                       qb_, kb_, vtb, yb);
    hipLaunchKernelGGL((gemm_bt<1>), dim3(64, 6), dim3(256), 0, stream,
                       yb, Wpb, b_proj, (bf16*)nullptr, (bf16*)nullptr, (bf16*)nullptr, out, 8192, 768, 768);
}